// Round 6
// baseline (1059.943 us; speedup 1.0000x reference)
//
#include <hip/hip_runtime.h>
#include <math.h>

#define N 8192
#define C 128
#define NC 256
#define KNN 5

#define CH2 32                       // channels per f64 staging chunk
#define PD 65                        // LDS pitch in doubles
#define TSP 65                       // Ts pitch in doubles (symA epilogue)
#define SQRT_C 11.313708498984761    // sqrt(128)
#define NTILE (N / 64)               // 128
#define NPAIR (NTILE * (NTILE + 1) / 2)   // 8256

static __device__ __forceinline__ unsigned rotl32(unsigned x, unsigned r) {
    return (x << r) | (x >> (32u - r));
}

// order-preserving double -> uint64 map (ascending)
static __device__ __forceinline__ unsigned long long dmap(double x) {
    long long b = __double_as_longlong(x);
    unsigned long long u = (unsigned long long)b;
    return (b >= 0) ? (u | 0x8000000000000000ull) : ~u;
}
static __device__ __forceinline__ double dunmap(unsigned long long u) {
    if (u & 0x8000000000000000ull) return __longlong_as_double((long long)(u ^ 0x8000000000000000ull));
    return __longlong_as_double((long long)(~u));
}

// keep 5 smallest; m5[0] holds current max of the 5
static __device__ __forceinline__ void ins5(double (&m5)[KNN], double v) {
    if (v < m5[0]) {
        m5[0] = v;
        #pragma unroll
        for (int k = 1; k < KNN; k++)
            if (m5[k] > m5[0]) { double tmp = m5[0]; m5[0] = m5[k]; m5[k] = tmp; }
    }
}

// ---------------------------------------------------------------------------
__global__ void init_kernel(unsigned long long* d2max, unsigned long long* gmin) {
    int i = blockIdx.x * blockDim.x + threadIdx.x;
    if (i < N) gmin[i] = 0xFFFFFFFFFFFFFFFFull;
    if (i == 0) *d2max = 0ull;
}

// ---------------------------------------------------------------------------
__global__ void sq_kernel(const float* __restrict__ X, double* __restrict__ sq) {
    int wave = (blockIdx.x * blockDim.x + threadIdx.x) >> 6;
    int lane = threadIdx.x & 63;
    if (wave >= N) return;
    double v0 = (double)X[wave * C + lane];
    double v1 = (double)X[wave * C + 64 + lane];
    double s = v0 * v0 + v1 * v1;
    #pragma unroll
    for (int off = 32; off > 0; off >>= 1) s += __shfl_down(s, off, 64);
    if (lane == 0) sq[wave] = s;
}

// ---------------------------------------------------------------------------
// JAX threefry2x32: uniform(key(1), (1,8192))
// ---------------------------------------------------------------------------
__global__ void noise_kernel(float* __restrict__ noise) {
    int j = blockIdx.x * blockDim.x + threadIdx.x;
    if (j >= N / 2) return;
    const unsigned ks0 = 0u, ks1 = 1u;
    const unsigned ks2 = 0x1BD11BDAu ^ ks0 ^ ks1;
    unsigned x0 = (unsigned)j + ks0;
    unsigned x1 = (unsigned)(j + N / 2) + ks1;
    const unsigned rotA[4] = {13u, 15u, 26u, 6u};
    const unsigned rotB[4] = {17u, 29u, 16u, 24u};
    #pragma unroll
    for (int r = 0; r < 4; r++) { x0 += x1; x1 = rotl32(x1, rotA[r]); x1 ^= x0; }
    x0 += ks1; x1 += ks2 + 1u;
    #pragma unroll
    for (int r = 0; r < 4; r++) { x0 += x1; x1 = rotl32(x1, rotB[r]); x1 ^= x0; }
    x0 += ks2; x1 += ks0 + 2u;
    #pragma unroll
    for (int r = 0; r < 4; r++) { x0 += x1; x1 = rotl32(x1, rotA[r]); x1 ^= x0; }
    x0 += ks0; x1 += ks1 + 3u;
    #pragma unroll
    for (int r = 0; r < 4; r++) { x0 += x1; x1 = rotl32(x1, rotB[r]); x1 ^= x0; }
    x0 += ks1; x1 += ks2 + 4u;
    #pragma unroll
    for (int r = 0; r < 4; r++) { x0 += x1; x1 = rotl32(x1, rotA[r]); x1 ^= x0; }
    x0 += ks2; x1 += ks0 + 5u;
    unsigned b0 = (x0 >> 9) | 0x3f800000u;
    unsigned b1 = (x1 >> 9) | 0x3f800000u;
    noise[j]         = __uint_as_float(b0) - 1.0f;
    noise[j + N / 2] = __uint_as_float(b1) - 1.0f;
}

// p = bj*(bj+1)/2 + bi, bi <= bj
static __device__ __forceinline__ void pair_decode(int p, int& bi, int& bj) {
    int b = (int)((sqrt(8.0 * (double)p + 1.0) - 1.0) * 0.5);
    while ((b + 1) * (b + 2) / 2 <= p) b++;
    while (b * (b + 1) / 2 > p) b--;
    bj = b;
    bi = p - b * (b + 1) / 2;
}

// ---------------------------------------------------------------------------
// symA: 64x64 tile-pair d2 GEMM.  LDS staged as f64 (cvt once at staging),
// 4 chunks of 32 channels, register prefetch.  4-wave half-split top-5 scan.
// ---------------------------------------------------------------------------
__launch_bounds__(256, 4)
__global__ void symA_kernel(const float* __restrict__ X,
                            const double* __restrict__ sq,
                            double* __restrict__ rec_dir,
                            double* __restrict__ rec_tr,
                            unsigned long long* __restrict__ d2max_p)
{
    __shared__ __align__(16) double S[2 * CH2 * PD];   // 33,280 B; reused as Ts[64][65]
    __shared__ double H[2][64][KNN];                   // 5,120 B half-merge
    __shared__ double wmax[2];
    double* As = S;
    double* Bs = S + CH2 * PD;

    const int t  = threadIdx.x;
    const int tx = t & 15;
    const int ty = t >> 4;
    int bi, bj;
    pair_decode(blockIdx.x, bi, bj);
    const int i0 = bi * 64, j0 = bj * 64;
    const float4* X4 = (const float4*)X;

    // chunk prefetch regs: 2 float4 per side (flat = t+256q: row = f>>3, c4 = f&7)
    float4 pa[2], pb[2];
    #pragma unroll
    for (int q = 0; q < 2; q++) {
        int flat = t + 256 * q, row = flat >> 3, c4 = flat & 7;
        pa[q] = X4[(size_t)(i0 + row) * 32 + c4];
        pb[q] = X4[(size_t)(j0 + row) * 32 + c4];
    }
    double sqa[4], sqj[4];
    #pragma unroll
    for (int r = 0; r < 4; r++) { sqa[r] = sq[i0 + 4 * ty + r]; sqj[r] = sq[j0 + 4 * tx + r]; }

    double acc[4][4];
    #pragma unroll
    for (int r = 0; r < 4; r++)
        #pragma unroll
        for (int s = 0; s < 4; s++) acc[r][s] = 0.0;

    for (int ck = 0; ck < 4; ck++) {
        // store prefetched chunk as f64, transposed [c][i]
        #pragma unroll
        for (int q = 0; q < 2; q++) {
            int flat = t + 256 * q, row = flat >> 3, c4 = flat & 7;
            double* da = &As[(4 * c4) * PD + row];
            double* db = &Bs[(4 * c4) * PD + row];
            da[0 * PD] = (double)pa[q].x; da[1 * PD] = (double)pa[q].y;
            da[2 * PD] = (double)pa[q].z; da[3 * PD] = (double)pa[q].w;
            db[0 * PD] = (double)pb[q].x; db[1 * PD] = (double)pb[q].y;
            db[2 * PD] = (double)pb[q].z; db[3 * PD] = (double)pb[q].w;
        }
        __syncthreads();
        if (ck < 3) {   // issue next chunk's global loads; drain at next store
            #pragma unroll
            for (int q = 0; q < 2; q++) {
                int flat = t + 256 * q, row = flat >> 3, c4 = flat & 7;
                pa[q] = X4[(size_t)(i0 + row) * 32 + (ck + 1) * 8 + c4];
                pb[q] = X4[(size_t)(j0 + row) * 32 + (ck + 1) * 8 + c4];
            }
        }
        #pragma unroll 4
        for (int c = 0; c < CH2; c++) {
            const double* ap = &As[c * PD + 4 * ty];
            const double* bp = &Bs[c * PD + 4 * tx];
            double a0 = ap[0], a1 = ap[1], a2 = ap[2], a3 = ap[3];
            double b0 = bp[0], b1 = bp[1], b2 = bp[2], b3 = bp[3];
            acc[0][0] += a0 * b0; acc[0][1] += a0 * b1; acc[0][2] += a0 * b2; acc[0][3] += a0 * b3;
            acc[1][0] += a1 * b0; acc[1][1] += a1 * b1; acc[1][2] += a1 * b2; acc[1][3] += a1 * b3;
            acc[2][0] += a2 * b0; acc[2][1] += a2 * b1; acc[2][2] += a2 * b2; acc[2][3] += a2 * b3;
            acc[3][0] += a3 * b0; acc[3][1] += a3 * b1; acc[3][2] += a3 * b2; acc[3][3] += a3 * b3;
        }
        __syncthreads();
    }

    double* Ts = S;   // [64][TSP]
    #pragma unroll
    for (int r = 0; r < 4; r++)
        #pragma unroll
        for (int s = 0; s < 4; s++)
            Ts[(4 * ty + r) * TSP + 4 * tx + s] = sqa[r] + sqj[s] - 2.0 * acc[r][s];
    __syncthreads();

    // 4-wave half-split scan: waves 0,1 rows (halves), waves 2,3 cols (halves)
    double m5[KNN];
    #pragma unroll
    for (int k = 0; k < KNN; k++) m5[k] = 1e300;
    double rmax = 0.0;
    const int side = t >> 7, h = (t >> 6) & 1, ln = t & 63;
    if (side == 0) {
        const double* rowp = &Ts[ln * TSP + 32 * h];
        for (int jj = 0; jj < 32; jj++) {
            double v = rowp[jj];
            rmax = fmax(rmax, v);
            ins5(m5, v);
        }
    } else if (bi != bj) {
        for (int ii = 0; ii < 32; ii++) ins5(m5, Ts[(32 * h + ii) * TSP + ln]);
    }
    double wm = rmax;
    #pragma unroll
    for (int off = 32; off > 0; off >>= 1) wm = fmax(wm, __shfl_down(wm, off, 64));
    if ((t & 63) == 0 && side == 0) wmax[h] = wm;
    if (h == 1) {
        #pragma unroll
        for (int k = 0; k < KNN; k++) H[side][ln][k] = m5[k];
    }
    __syncthreads();
    if (h == 0) {
        #pragma unroll
        for (int k = 0; k < KNN; k++) ins5(m5, H[side][ln][k]);
        if (side == 0) {
            double* outp = &rec_dir[(size_t)blockIdx.x * 320 + ln * KNN];
            #pragma unroll
            for (int k = 0; k < KNN; k++) outp[k] = m5[k];
        } else if (bi != bj) {
            double* outp = &rec_tr[(size_t)blockIdx.x * 320 + ln * KNN];
            #pragma unroll
            for (int k = 0; k < KNN; k++) outp[k] = m5[k];
        }
    }
    if (t == 0)
        atomicMax(d2max_p, (unsigned long long)__double_as_longlong(
            fmax(fmax(wmax[0], wmax[1]), 0.0)));
}

// ---------------------------------------------------------------------------
// Merge symA records -> density (proven).
// ---------------------------------------------------------------------------
__global__ void density_merge_sym_kernel(const double* __restrict__ rec_dir,
                                         const double* __restrict__ rec_tr,
                                         const float* __restrict__ noise,
                                         double* __restrict__ density)
{
    int i = blockIdx.x * blockDim.x + threadIdx.x;
    if (i >= N) return;
    int T = i >> 6, r = i & 63;
    double t5[KNN];
    #pragma unroll
    for (int k = 0; k < KNN; k++) t5[k] = 1e300;

    for (int bj = T; bj < NTILE; bj++) {
        int p = bj * (bj + 1) / 2 + T;
        const double* rp = &rec_dir[(size_t)p * 320 + r * KNN];
        #pragma unroll
        for (int k = 0; k < KNN; k++) ins5(t5, rp[k]);
    }
    int cumT = T * (T + 1) / 2;
    for (int bi = 0; bi < T; bi++) {
        const double* rp = &rec_tr[(size_t)(cumT + bi) * 320 + r * KNN];
        #pragma unroll
        for (int k = 0; k < KNN; k++) ins5(t5, rp[k]);
    }
    for (int a = 1; a < KNN; a++) {
        double key = t5[a]; int b = a - 1;
        while (b >= 0 && t5[b] > key) { t5[b + 1] = t5[b]; b--; }
        t5[b + 1] = key;
    }
    double s2 = 0.0;
    #pragma unroll
    for (int k = 0; k < KNN; k++) {
        double z = t5[k] > 0.0 ? t5[k] : 0.0;
        double d = sqrt(z) / SQRT_C;
        s2 += d * d;
    }
    density[i] = exp(-s2 / 5.0) + (double)(noise[i] * 1e-6f);
}

// ---------------------------------------------------------------------------
// symB: same f64-staged GEMM; masked min in register epilogue; atomicMin merge.
// ---------------------------------------------------------------------------
__launch_bounds__(256, 4)
__global__ void symB_kernel(const float* __restrict__ X,
                            const double* __restrict__ sq,
                            const double* __restrict__ density,
                            unsigned long long* __restrict__ gmin)
{
    __shared__ __align__(16) double S[2 * CH2 * PD];   // reused as Mr/Mc
    __shared__ double Drow[64], Dcol[64];
    double* As = S;
    double* Bs = S + CH2 * PD;

    const int t  = threadIdx.x;
    const int tx = t & 15;
    const int ty = t >> 4;
    int bi, bj;
    pair_decode(blockIdx.x, bi, bj);
    const int i0 = bi * 64, j0 = bj * 64;
    const float4* X4 = (const float4*)X;

    if (t < 64) Drow[t] = density[i0 + t];
    else if (t < 128) Dcol[t - 64] = density[j0 + t - 64];

    float4 pa[2], pb[2];
    #pragma unroll
    for (int q = 0; q < 2; q++) {
        int flat = t + 256 * q, row = flat >> 3, c4 = flat & 7;
        pa[q] = X4[(size_t)(i0 + row) * 32 + c4];
        pb[q] = X4[(size_t)(j0 + row) * 32 + c4];
    }
    double sqa[4], sqj[4];
    #pragma unroll
    for (int r = 0; r < 4; r++) { sqa[r] = sq[i0 + 4 * ty + r]; sqj[r] = sq[j0 + 4 * tx + r]; }

    double acc[4][4];
    #pragma unroll
    for (int r = 0; r < 4; r++)
        #pragma unroll
        for (int s = 0; s < 4; s++) acc[r][s] = 0.0;

    for (int ck = 0; ck < 4; ck++) {
        #pragma unroll
        for (int q = 0; q < 2; q++) {
            int flat = t + 256 * q, row = flat >> 3, c4 = flat & 7;
            double* da = &As[(4 * c4) * PD + row];
            double* db = &Bs[(4 * c4) * PD + row];
            da[0 * PD] = (double)pa[q].x; da[1 * PD] = (double)pa[q].y;
            da[2 * PD] = (double)pa[q].z; da[3 * PD] = (double)pa[q].w;
            db[0 * PD] = (double)pb[q].x; db[1 * PD] = (double)pb[q].y;
            db[2 * PD] = (double)pb[q].z; db[3 * PD] = (double)pb[q].w;
        }
        __syncthreads();
        if (ck < 3) {
            #pragma unroll
            for (int q = 0; q < 2; q++) {
                int flat = t + 256 * q, row = flat >> 3, c4 = flat & 7;
                pa[q] = X4[(size_t)(i0 + row) * 32 + (ck + 1) * 8 + c4];
                pb[q] = X4[(size_t)(j0 + row) * 32 + (ck + 1) * 8 + c4];
            }
        }
        #pragma unroll 4
        for (int c = 0; c < CH2; c++) {
            const double* ap = &As[c * PD + 4 * ty];
            const double* bp = &Bs[c * PD + 4 * tx];
            double a0 = ap[0], a1 = ap[1], a2 = ap[2], a3 = ap[3];
            double b0 = bp[0], b1 = bp[1], b2 = bp[2], b3 = bp[3];
            acc[0][0] += a0 * b0; acc[0][1] += a0 * b1; acc[0][2] += a0 * b2; acc[0][3] += a0 * b3;
            acc[1][0] += a1 * b0; acc[1][1] += a1 * b1; acc[1][2] += a1 * b2; acc[1][3] += a1 * b3;
            acc[2][0] += a2 * b0; acc[2][1] += a2 * b1; acc[2][2] += a2 * b2; acc[2][3] += a2 * b3;
            acc[3][0] += a3 * b0; acc[3][1] += a3 * b1; acc[3][2] += a3 * b2; acc[3][3] += a3 * b3;
        }
        __syncthreads();
    }

    // register epilogue: masked row/col mins
    double di[4], dj[4], dmr[4], dmc[4];
    #pragma unroll
    for (int r = 0; r < 4; r++) { di[r] = Drow[4 * ty + r]; dmr[r] = 1e300; }
    #pragma unroll
    for (int s = 0; s < 4; s++) { dj[s] = Dcol[4 * tx + s]; dmc[s] = 1e300; }
    #pragma unroll
    for (int r = 0; r < 4; r++)
        #pragma unroll
        for (int s = 0; s < 4; s++) {
            double v = sqa[r] + sqj[s] - 2.0 * acc[r][s];
            if (dj[s] > di[r]) dmr[r] = fmin(dmr[r], v);
            if (di[r] > dj[s]) dmc[s] = fmin(dmc[s], v);
        }

    double* Mr = S;                     // [64][17]
    double* Mc = Mr + 64 * 17;          // [64][17]
    #pragma unroll
    for (int r = 0; r < 4; r++) Mr[(4 * ty + r) * 17 + tx] = dmr[r];
    #pragma unroll
    for (int s = 0; s < 4; s++) Mc[(4 * tx + s) * 17 + ty] = dmc[s];
    __syncthreads();

    if (t < 64) {
        double m = 1e300;
        const double* row = &Mr[t * 17];
        #pragma unroll
        for (int q = 0; q < 16; q++) m = fmin(m, row[q]);
        if (m < 9.9e299) atomicMin(&gmin[i0 + t], dmap(m));
    } else if (t < 128 && bi != bj) {
        int c = t - 64;
        double m = 1e300;
        const double* row = &Mc[c * 17];
        #pragma unroll
        for (int q = 0; q < 16; q++) m = fmin(m, row[q]);
        if (m < 9.9e299) atomicMin(&gmin[j0 + c], dmap(m));
    }
}

// ---------------------------------------------------------------------------
__global__ void score_sym_kernel(const unsigned long long* __restrict__ gmin,
                                 const double* __restrict__ density,
                                 const unsigned long long* __restrict__ d2max_p,
                                 double* __restrict__ score)
{
    int i = blockIdx.x * blockDim.x + threadIdx.x;
    if (i >= N) return;
    unsigned long long u = gmin[i];
    double d2m = __longlong_as_double((long long)(*d2max_p));
    double distmax = sqrt(fmax(d2m, 0.0)) / SQRT_C;
    double dp;
    if (u == 0xFFFFFFFFFFFFFFFFull) {
        dp = distmax;
    } else {
        double dmin = dunmap(u);
        dp = sqrt(fmax(dmin, 0.0)) / SQRT_C;
    }
    score[i] = dp * density[i];
}

// ---------------------------------------------------------------------------
// Stable descending rank; 256 blocks, 8-way j-split per row, shuffle reduce.
// ---------------------------------------------------------------------------
__launch_bounds__(256)
__global__ void rank_kernel(const double* __restrict__ score, int* __restrict__ out)
{
    __shared__ double Ss[N];   // 64 KB
    for (int k = 0; k < N / 256; k++) {
        int idx = threadIdx.x + 256 * k;
        Ss[idx] = score[idx];
    }
    __syncthreads();
    int il = threadIdx.x >> 3;          // 0..31
    int ch = threadIdx.x & 7;           // 0..7
    int i = blockIdx.x * 32 + il;
    double si = Ss[i];
    int cnt = 0;
    for (int q = 0; q < N / 8; q++) {
        int j = ch + (q << 3);
        double sj = Ss[j];
        cnt += (sj > si) || (sj == si && j < i);
    }
    cnt += __shfl_down(cnt, 4, 8);
    cnt += __shfl_down(cnt, 2, 8);
    cnt += __shfl_down(cnt, 1, 8);
    if (ch == 0 && cnt < NC) out[cnt] = i;
}

// ---------------------------------------------------------------------------
extern "C" void kernel_launch(void* const* d_in, const int* in_sizes, int n_in,
                              void* d_out, int out_size, void* d_ws, size_t ws_size,
                              hipStream_t stream) {
    const float* X = (const float*)d_in[0];
    int* out = (int*)d_out;

    double* ws      = (double*)d_ws;
    double* sq      = ws;                      // 8192
    double* density = ws + 8192;               // 8192
    double* score   = ws + 16384;              // 8192
    unsigned long long* d2max = (unsigned long long*)(ws + 24576);
    unsigned long long* gmin  = (unsigned long long*)(ws + 24584);  // 8192
    float*  noise   = (float*)(ws + 32776);    // 8192 floats

    const size_t rec_bytes = (size_t)NPAIR * 64 * KNN * sizeof(double);  // 21.1 MB
    const size_t base_need = 4ull * 1024 * 1024;
    // R4/R5 confirmed ws_size >= base_need + 2*rec_bytes (records written, passed).
    double* rec_dir = (double*)((char*)d_ws + base_need);
    double* rec_tr  = (double*)((char*)d_ws + base_need + rec_bytes);

    init_kernel<<<N / 256, 256, 0, stream>>>(d2max, gmin);
    sq_kernel<<<N / 4, 256, 0, stream>>>(X, sq);
    noise_kernel<<<(N / 2) / 256, 256, 0, stream>>>(noise);

    symA_kernel<<<NPAIR, 256, 0, stream>>>(X, sq, rec_dir, rec_tr, d2max);
    density_merge_sym_kernel<<<N / 256, 256, 0, stream>>>(rec_dir, rec_tr, noise, density);
    symB_kernel<<<NPAIR, 256, 0, stream>>>(X, sq, density, gmin);
    score_sym_kernel<<<N / 256, 256, 0, stream>>>(gmin, density, d2max, score);
    rank_kernel<<<N / 32, 256, 0, stream>>>(score, out);
}

// Round 7
// 725.657 us; speedup vs baseline: 1.4607x; 1.4607x over previous
//
#include <hip/hip_runtime.h>
#include <math.h>

#define N 8192
#define C 128
#define NC 256
#define KNN 5

#define CH2 32                       // channels per f64 staging chunk
#define PD 65                        // LDS pitch in doubles
#define TSP 65                       // Ts pitch in doubles (symA epilogue)
#define SQRT_C 11.313708498984761    // sqrt(128)
#define NTILE (N / 64)               // 128
#define NPAIR (NTILE * (NTILE + 1) / 2)   // 8256

static __device__ __forceinline__ unsigned rotl32(unsigned x, unsigned r) {
    return (x << r) | (x >> (32u - r));
}

// order-preserving double -> uint64 map (ascending)
static __device__ __forceinline__ unsigned long long dmap(double x) {
    long long b = __double_as_longlong(x);
    unsigned long long u = (unsigned long long)b;
    return (b >= 0) ? (u | 0x8000000000000000ull) : ~u;
}
static __device__ __forceinline__ double dunmap(unsigned long long u) {
    if (u & 0x8000000000000000ull) return __longlong_as_double((long long)(u ^ 0x8000000000000000ull));
    return __longlong_as_double((long long)(~u));
}

// keep 5 smallest; m5[0] holds current max of the 5
static __device__ __forceinline__ void ins5(double (&m5)[KNN], double v) {
    if (v < m5[0]) {
        m5[0] = v;
        #pragma unroll
        for (int k = 1; k < KNN; k++)
            if (m5[k] > m5[0]) { double tmp = m5[0]; m5[0] = m5[k]; m5[k] = tmp; }
    }
}

// ---------------------------------------------------------------------------
__global__ void init_kernel(unsigned long long* d2max, unsigned long long* gmin) {
    int i = blockIdx.x * blockDim.x + threadIdx.x;
    if (i < N) gmin[i] = 0xFFFFFFFFFFFFFFFFull;
    if (i == 0) *d2max = 0ull;
}

// ---------------------------------------------------------------------------
__global__ void sq_kernel(const float* __restrict__ X, double* __restrict__ sq) {
    int wave = (blockIdx.x * blockDim.x + threadIdx.x) >> 6;
    int lane = threadIdx.x & 63;
    if (wave >= N) return;
    double v0 = (double)X[wave * C + lane];
    double v1 = (double)X[wave * C + 64 + lane];
    double s = v0 * v0 + v1 * v1;
    #pragma unroll
    for (int off = 32; off > 0; off >>= 1) s += __shfl_down(s, off, 64);
    if (lane == 0) sq[wave] = s;
}

// ---------------------------------------------------------------------------
// JAX threefry2x32: uniform(key(1), (1,8192))
// ---------------------------------------------------------------------------
__global__ void noise_kernel(float* __restrict__ noise) {
    int j = blockIdx.x * blockDim.x + threadIdx.x;
    if (j >= N / 2) return;
    const unsigned ks0 = 0u, ks1 = 1u;
    const unsigned ks2 = 0x1BD11BDAu ^ ks0 ^ ks1;
    unsigned x0 = (unsigned)j + ks0;
    unsigned x1 = (unsigned)(j + N / 2) + ks1;
    const unsigned rotA[4] = {13u, 15u, 26u, 6u};
    const unsigned rotB[4] = {17u, 29u, 16u, 24u};
    #pragma unroll
    for (int r = 0; r < 4; r++) { x0 += x1; x1 = rotl32(x1, rotA[r]); x1 ^= x0; }
    x0 += ks1; x1 += ks2 + 1u;
    #pragma unroll
    for (int r = 0; r < 4; r++) { x0 += x1; x1 = rotl32(x1, rotB[r]); x1 ^= x0; }
    x0 += ks2; x1 += ks0 + 2u;
    #pragma unroll
    for (int r = 0; r < 4; r++) { x0 += x1; x1 = rotl32(x1, rotA[r]); x1 ^= x0; }
    x0 += ks0; x1 += ks1 + 3u;
    #pragma unroll
    for (int r = 0; r < 4; r++) { x0 += x1; x1 = rotl32(x1, rotB[r]); x1 ^= x0; }
    x0 += ks1; x1 += ks2 + 4u;
    #pragma unroll
    for (int r = 0; r < 4; r++) { x0 += x1; x1 = rotl32(x1, rotA[r]); x1 ^= x0; }
    x0 += ks2; x1 += ks0 + 5u;
    unsigned b0 = (x0 >> 9) | 0x3f800000u;
    unsigned b1 = (x1 >> 9) | 0x3f800000u;
    noise[j]         = __uint_as_float(b0) - 1.0f;
    noise[j + N / 2] = __uint_as_float(b1) - 1.0f;
}

// p = bj*(bj+1)/2 + bi, bi <= bj
static __device__ __forceinline__ void pair_decode(int p, int& bi, int& bj) {
    int b = (int)((sqrt(8.0 * (double)p + 1.0) - 1.0) * 0.5);
    while ((b + 1) * (b + 2) / 2 <= p) b++;
    while (b * (b + 1) / 2 > p) b--;
    bj = b;
    bi = p - b * (b + 1) / 2;
}

// ---------------------------------------------------------------------------
// symA: 64x64 tile-pair d2 GEMM.  f64 LDS staging (cvt once), interleaved
// column tile (tx, tx+16, tx+32, tx+48) -> conflict-free B reads.
// 4-wave half-split top-5 scan.
// ---------------------------------------------------------------------------
__launch_bounds__(256, 4)
__global__ void symA_kernel(const float* __restrict__ X,
                            const double* __restrict__ sq,
                            double* __restrict__ rec_dir,
                            double* __restrict__ rec_tr,
                            unsigned long long* __restrict__ d2max_p)
{
    __shared__ __align__(16) double S[2 * CH2 * PD];   // 33,280 B; reused as Ts[64][65]
    __shared__ double H[2][64][KNN];                   // 5,120 B half-merge
    __shared__ double wmax[2];
    double* As = S;
    double* Bs = S + CH2 * PD;

    const int t  = threadIdx.x;
    const int tx = t & 15;
    const int ty = t >> 4;
    int bi, bj;
    pair_decode(blockIdx.x, bi, bj);
    const int i0 = bi * 64, j0 = bj * 64;
    const float4* X4 = (const float4*)X;

    float4 pa[2], pb[2];
    #pragma unroll
    for (int q = 0; q < 2; q++) {
        int flat = t + 256 * q, row = flat >> 3, c4 = flat & 7;
        pa[q] = X4[(size_t)(i0 + row) * 32 + c4];
        pb[q] = X4[(size_t)(j0 + row) * 32 + c4];
    }
    double sqa[4], sqj[4];
    #pragma unroll
    for (int r = 0; r < 4; r++) sqa[r] = sq[i0 + 4 * ty + r];
    #pragma unroll
    for (int s = 0; s < 4; s++) sqj[s] = sq[j0 + tx + 16 * s];

    double acc[4][4];
    #pragma unroll
    for (int r = 0; r < 4; r++)
        #pragma unroll
        for (int s = 0; s < 4; s++) acc[r][s] = 0.0;

    for (int ck = 0; ck < 4; ck++) {
        #pragma unroll
        for (int q = 0; q < 2; q++) {
            int flat = t + 256 * q, row = flat >> 3, c4 = flat & 7;
            double* da = &As[(4 * c4) * PD + row];
            double* db = &Bs[(4 * c4) * PD + row];
            da[0 * PD] = (double)pa[q].x; da[1 * PD] = (double)pa[q].y;
            da[2 * PD] = (double)pa[q].z; da[3 * PD] = (double)pa[q].w;
            db[0 * PD] = (double)pb[q].x; db[1 * PD] = (double)pb[q].y;
            db[2 * PD] = (double)pb[q].z; db[3 * PD] = (double)pb[q].w;
        }
        __syncthreads();
        if (ck < 3) {
            #pragma unroll
            for (int q = 0; q < 2; q++) {
                int flat = t + 256 * q, row = flat >> 3, c4 = flat & 7;
                pa[q] = X4[(size_t)(i0 + row) * 32 + (ck + 1) * 8 + c4];
                pb[q] = X4[(size_t)(j0 + row) * 32 + (ck + 1) * 8 + c4];
            }
        }
        #pragma unroll 4
        for (int c = 0; c < CH2; c++) {
            const double* ap = &As[c * PD + 4 * ty];
            const double* bp = &Bs[c * PD + tx];
            double a0 = ap[0], a1 = ap[1], a2 = ap[2], a3 = ap[3];
            double b0 = bp[0], b1 = bp[16], b2 = bp[32], b3 = bp[48];
            acc[0][0] += a0 * b0; acc[0][1] += a0 * b1; acc[0][2] += a0 * b2; acc[0][3] += a0 * b3;
            acc[1][0] += a1 * b0; acc[1][1] += a1 * b1; acc[1][2] += a1 * b2; acc[1][3] += a1 * b3;
            acc[2][0] += a2 * b0; acc[2][1] += a2 * b1; acc[2][2] += a2 * b2; acc[2][3] += a2 * b3;
            acc[3][0] += a3 * b0; acc[3][1] += a3 * b1; acc[3][2] += a3 * b2; acc[3][3] += a3 * b3;
        }
        __syncthreads();
    }

    double* Ts = S;   // [64][TSP]
    #pragma unroll
    for (int r = 0; r < 4; r++)
        #pragma unroll
        for (int s = 0; s < 4; s++)
            Ts[(4 * ty + r) * TSP + tx + 16 * s] = sqa[r] + sqj[s] - 2.0 * acc[r][s];
    __syncthreads();

    // 4-wave half-split scan: waves 0,1 rows (halves), waves 2,3 cols (halves)
    double m5[KNN];
    #pragma unroll
    for (int k = 0; k < KNN; k++) m5[k] = 1e300;
    double rmax = 0.0;
    const int side = t >> 7, h = (t >> 6) & 1, ln = t & 63;
    if (side == 0) {
        const double* rowp = &Ts[ln * TSP + 32 * h];
        for (int jj = 0; jj < 32; jj++) {
            double v = rowp[jj];
            rmax = fmax(rmax, v);
            ins5(m5, v);
        }
    } else if (bi != bj) {
        for (int ii = 0; ii < 32; ii++) ins5(m5, Ts[(32 * h + ii) * TSP + ln]);
    }
    double wm = rmax;
    #pragma unroll
    for (int off = 32; off > 0; off >>= 1) wm = fmax(wm, __shfl_down(wm, off, 64));
    if ((t & 63) == 0 && side == 0) wmax[h] = wm;
    if (h == 1) {
        #pragma unroll
        for (int k = 0; k < KNN; k++) H[side][ln][k] = m5[k];
    }
    __syncthreads();
    if (h == 0) {
        #pragma unroll
        for (int k = 0; k < KNN; k++) ins5(m5, H[side][ln][k]);
        if (side == 0) {
            double* outp = &rec_dir[(size_t)blockIdx.x * 320 + ln * KNN];
            #pragma unroll
            for (int k = 0; k < KNN; k++) outp[k] = m5[k];
        } else if (bi != bj) {
            double* outp = &rec_tr[(size_t)blockIdx.x * 320 + ln * KNN];
            #pragma unroll
            for (int k = 0; k < KNN; k++) outp[k] = m5[k];
        }
    }
    if (t == 0)
        atomicMax(d2max_p, (unsigned long long)__double_as_longlong(
            fmax(fmax(wmax[0], wmax[1]), 0.0)));
}

// ---------------------------------------------------------------------------
// Merge symA records -> density (proven).
// ---------------------------------------------------------------------------
__global__ void density_merge_sym_kernel(const double* __restrict__ rec_dir,
                                         const double* __restrict__ rec_tr,
                                         const float* __restrict__ noise,
                                         double* __restrict__ density)
{
    int i = blockIdx.x * blockDim.x + threadIdx.x;
    if (i >= N) return;
    int T = i >> 6, r = i & 63;
    double t5[KNN];
    #pragma unroll
    for (int k = 0; k < KNN; k++) t5[k] = 1e300;

    for (int bj = T; bj < NTILE; bj++) {
        int p = bj * (bj + 1) / 2 + T;
        const double* rp = &rec_dir[(size_t)p * 320 + r * KNN];
        #pragma unroll
        for (int k = 0; k < KNN; k++) ins5(t5, rp[k]);
    }
    int cumT = T * (T + 1) / 2;
    for (int bi = 0; bi < T; bi++) {
        const double* rp = &rec_tr[(size_t)(cumT + bi) * 320 + r * KNN];
        #pragma unroll
        for (int k = 0; k < KNN; k++) ins5(t5, rp[k]);
    }
    for (int a = 1; a < KNN; a++) {
        double key = t5[a]; int b = a - 1;
        while (b >= 0 && t5[b] > key) { t5[b + 1] = t5[b]; b--; }
        t5[b + 1] = key;
    }
    double s2 = 0.0;
    #pragma unroll
    for (int k = 0; k < KNN; k++) {
        double z = t5[k] > 0.0 ? t5[k] : 0.0;
        double d = sqrt(z) / SQRT_C;
        s2 += d * d;
    }
    density[i] = exp(-s2 / 5.0) + (double)(noise[i] * 1e-6f);
}

// ---------------------------------------------------------------------------
// symB: same f64-staged GEMM with interleaved columns; masked min in
// register epilogue; atomicMin merge.
// ---------------------------------------------------------------------------
__launch_bounds__(256, 4)
__global__ void symB_kernel(const float* __restrict__ X,
                            const double* __restrict__ sq,
                            const double* __restrict__ density,
                            unsigned long long* __restrict__ gmin)
{
    __shared__ __align__(16) double S[2 * CH2 * PD];   // reused as Mr/Mc
    __shared__ double Drow[64], Dcol[64];
    double* As = S;
    double* Bs = S + CH2 * PD;

    const int t  = threadIdx.x;
    const int tx = t & 15;
    const int ty = t >> 4;
    int bi, bj;
    pair_decode(blockIdx.x, bi, bj);
    const int i0 = bi * 64, j0 = bj * 64;
    const float4* X4 = (const float4*)X;

    if (t < 64) Drow[t] = density[i0 + t];
    else if (t < 128) Dcol[t - 64] = density[j0 + t - 64];

    float4 pa[2], pb[2];
    #pragma unroll
    for (int q = 0; q < 2; q++) {
        int flat = t + 256 * q, row = flat >> 3, c4 = flat & 7;
        pa[q] = X4[(size_t)(i0 + row) * 32 + c4];
        pb[q] = X4[(size_t)(j0 + row) * 32 + c4];
    }
    double sqa[4], sqj[4];
    #pragma unroll
    for (int r = 0; r < 4; r++) sqa[r] = sq[i0 + 4 * ty + r];
    #pragma unroll
    for (int s = 0; s < 4; s++) sqj[s] = sq[j0 + tx + 16 * s];

    double acc[4][4];
    #pragma unroll
    for (int r = 0; r < 4; r++)
        #pragma unroll
        for (int s = 0; s < 4; s++) acc[r][s] = 0.0;

    for (int ck = 0; ck < 4; ck++) {
        #pragma unroll
        for (int q = 0; q < 2; q++) {
            int flat = t + 256 * q, row = flat >> 3, c4 = flat & 7;
            double* da = &As[(4 * c4) * PD + row];
            double* db = &Bs[(4 * c4) * PD + row];
            da[0 * PD] = (double)pa[q].x; da[1 * PD] = (double)pa[q].y;
            da[2 * PD] = (double)pa[q].z; da[3 * PD] = (double)pa[q].w;
            db[0 * PD] = (double)pb[q].x; db[1 * PD] = (double)pb[q].y;
            db[2 * PD] = (double)pb[q].z; db[3 * PD] = (double)pb[q].w;
        }
        __syncthreads();
        if (ck < 3) {
            #pragma unroll
            for (int q = 0; q < 2; q++) {
                int flat = t + 256 * q, row = flat >> 3, c4 = flat & 7;
                pa[q] = X4[(size_t)(i0 + row) * 32 + (ck + 1) * 8 + c4];
                pb[q] = X4[(size_t)(j0 + row) * 32 + (ck + 1) * 8 + c4];
            }
        }
        #pragma unroll 4
        for (int c = 0; c < CH2; c++) {
            const double* ap = &As[c * PD + 4 * ty];
            const double* bp = &Bs[c * PD + tx];
            double a0 = ap[0], a1 = ap[1], a2 = ap[2], a3 = ap[3];
            double b0 = bp[0], b1 = bp[16], b2 = bp[32], b3 = bp[48];
            acc[0][0] += a0 * b0; acc[0][1] += a0 * b1; acc[0][2] += a0 * b2; acc[0][3] += a0 * b3;
            acc[1][0] += a1 * b0; acc[1][1] += a1 * b1; acc[1][2] += a1 * b2; acc[1][3] += a1 * b3;
            acc[2][0] += a2 * b0; acc[2][1] += a2 * b1; acc[2][2] += a2 * b2; acc[2][3] += a2 * b3;
            acc[3][0] += a3 * b0; acc[3][1] += a3 * b1; acc[3][2] += a3 * b2; acc[3][3] += a3 * b3;
        }
        __syncthreads();
    }

    // register epilogue: masked row/col mins (cols are tx+16s)
    double di[4], dj[4], dmr[4], dmc[4];
    #pragma unroll
    for (int r = 0; r < 4; r++) { di[r] = Drow[4 * ty + r]; dmr[r] = 1e300; }
    #pragma unroll
    for (int s = 0; s < 4; s++) { dj[s] = Dcol[tx + 16 * s]; dmc[s] = 1e300; }
    #pragma unroll
    for (int r = 0; r < 4; r++)
        #pragma unroll
        for (int s = 0; s < 4; s++) {
            double v = sqa[r] + sqj[s] - 2.0 * acc[r][s];
            if (dj[s] > di[r]) dmr[r] = fmin(dmr[r], v);
            if (di[r] > dj[s]) dmc[s] = fmin(dmc[s], v);
        }

    double* Mr = S;                     // [64][17]
    double* Mc = Mr + 64 * 17;          // [64][17]
    #pragma unroll
    for (int r = 0; r < 4; r++) Mr[(4 * ty + r) * 17 + tx] = dmr[r];
    #pragma unroll
    for (int s = 0; s < 4; s++) Mc[(tx + 16 * s) * 17 + ty] = dmc[s];
    __syncthreads();

    if (t < 64) {
        double m = 1e300;
        const double* row = &Mr[t * 17];
        #pragma unroll
        for (int q = 0; q < 16; q++) m = fmin(m, row[q]);
        if (m < 9.9e299) atomicMin(&gmin[i0 + t], dmap(m));
    } else if (t < 128 && bi != bj) {
        int c = t - 64;
        double m = 1e300;
        const double* row = &Mc[c * 17];
        #pragma unroll
        for (int q = 0; q < 16; q++) m = fmin(m, row[q]);
        if (m < 9.9e299) atomicMin(&gmin[j0 + c], dmap(m));
    }
}

// ---------------------------------------------------------------------------
__global__ void score_sym_kernel(const unsigned long long* __restrict__ gmin,
                                 const double* __restrict__ density,
                                 const unsigned long long* __restrict__ d2max_p,
                                 double* __restrict__ score)
{
    int i = blockIdx.x * blockDim.x + threadIdx.x;
    if (i >= N) return;
    unsigned long long u = gmin[i];
    double d2m = __longlong_as_double((long long)(*d2max_p));
    double distmax = sqrt(fmax(d2m, 0.0)) / SQRT_C;
    double dp;
    if (u == 0xFFFFFFFFFFFFFFFFull) {
        dp = distmax;
    } else {
        double dmin = dunmap(u);
        dp = sqrt(fmax(dmin, 0.0)) / SQRT_C;
    }
    score[i] = dp * density[i];
}

// ---------------------------------------------------------------------------
// Stable descending rank; 256 blocks, 8-way j-split per row, shuffle reduce.
// ---------------------------------------------------------------------------
__launch_bounds__(256)
__global__ void rank_kernel(const double* __restrict__ score, int* __restrict__ out)
{
    __shared__ double Ss[N];   // 64 KB
    for (int k = 0; k < N / 256; k++) {
        int idx = threadIdx.x + 256 * k;
        Ss[idx] = score[idx];
    }
    __syncthreads();
    int il = threadIdx.x >> 3;          // 0..31
    int ch = threadIdx.x & 7;           // 0..7
    int i = blockIdx.x * 32 + il;
    double si = Ss[i];
    int cnt = 0;
    for (int q = 0; q < N / 8; q++) {
        int j = ch + (q << 3);
        double sj = Ss[j];
        cnt += (sj > si) || (sj == si && j < i);
    }
    cnt += __shfl_down(cnt, 4, 8);
    cnt += __shfl_down(cnt, 2, 8);
    cnt += __shfl_down(cnt, 1, 8);
    if (ch == 0 && cnt < NC) out[cnt] = i;
}

// ---------------------------------------------------------------------------
extern "C" void kernel_launch(void* const* d_in, const int* in_sizes, int n_in,
                              void* d_out, int out_size, void* d_ws, size_t ws_size,
                              hipStream_t stream) {
    const float* X = (const float*)d_in[0];
    int* out = (int*)d_out;

    double* ws      = (double*)d_ws;
    double* sq      = ws;                      // 8192
    double* density = ws + 8192;               // 8192
    double* score   = ws + 16384;              // 8192
    unsigned long long* d2max = (unsigned long long*)(ws + 24576);
    unsigned long long* gmin  = (unsigned long long*)(ws + 24584);  // 8192
    float*  noise   = (float*)(ws + 32776);    // 8192 floats

    const size_t rec_bytes = (size_t)NPAIR * 64 * KNN * sizeof(double);  // 21.1 MB
    const size_t base_need = 4ull * 1024 * 1024;
    // R4/R5/R6 confirmed ws_size >= base_need + 2*rec_bytes.
    double* rec_dir = (double*)((char*)d_ws + base_need);
    double* rec_tr  = (double*)((char*)d_ws + base_need + rec_bytes);

    init_kernel<<<N / 256, 256, 0, stream>>>(d2max, gmin);
    sq_kernel<<<N / 4, 256, 0, stream>>>(X, sq);
    noise_kernel<<<(N / 2) / 256, 256, 0, stream>>>(noise);

    symA_kernel<<<NPAIR, 256, 0, stream>>>(X, sq, rec_dir, rec_tr, d2max);
    density_merge_sym_kernel<<<N / 256, 256, 0, stream>>>(rec_dir, rec_tr, noise, density);
    symB_kernel<<<NPAIR, 256, 0, stream>>>(X, sq, density, gmin);
    score_sym_kernel<<<N / 256, 256, 0, stream>>>(gmin, density, d2max, score);
    rank_kernel<<<N / 32, 256, 0, stream>>>(score, out);
}

// Round 8
// 716.106 us; speedup vs baseline: 1.4801x; 1.0133x over previous
//
#include <hip/hip_runtime.h>
#include <math.h>

#define N 8192
#define C 128
#define NC 256
#define KNN 5

#define TP 128                        // tile size
#define NTILE (N / TP)                // 64
#define NPAIR (NTILE * (NTILE + 1) / 2)   // 2080
#define CH 32                         // channels per staging chunk
#define CP 33                         // LDS row pitch in doubles (CH + 1)
#define MP 81                         // symA merge pitch (odd)
#define SQRT_C 11.313708498984761     // sqrt(128)

static __device__ __forceinline__ unsigned rotl32(unsigned x, unsigned r) {
    return (x << r) | (x >> (32u - r));
}

// order-preserving double -> uint64 map (ascending)
static __device__ __forceinline__ unsigned long long dmap(double x) {
    long long b = __double_as_longlong(x);
    unsigned long long u = (unsigned long long)b;
    return (b >= 0) ? (u | 0x8000000000000000ull) : ~u;
}
static __device__ __forceinline__ double dunmap(unsigned long long u) {
    if (u & 0x8000000000000000ull) return __longlong_as_double((long long)(u ^ 0x8000000000000000ull));
    return __longlong_as_double((long long)(~u));
}

// keep 5 smallest; m5[0] holds current max of the 5
static __device__ __forceinline__ void ins5(double (&m5)[KNN], double v) {
    if (v < m5[0]) {
        m5[0] = v;
        #pragma unroll
        for (int k = 1; k < KNN; k++)
            if (m5[k] > m5[0]) { double tmp = m5[0]; m5[0] = m5[k]; m5[k] = tmp; }
    }
}

// ---------------------------------------------------------------------------
__global__ void init_kernel(unsigned long long* d2max, unsigned long long* gmin) {
    int i = blockIdx.x * blockDim.x + threadIdx.x;
    if (i < N) gmin[i] = 0xFFFFFFFFFFFFFFFFull;
    if (i == 0) *d2max = 0ull;
}

// ---------------------------------------------------------------------------
__global__ void sq_kernel(const float* __restrict__ X, double* __restrict__ sq) {
    int wave = (blockIdx.x * blockDim.x + threadIdx.x) >> 6;
    int lane = threadIdx.x & 63;
    if (wave >= N) return;
    double v0 = (double)X[wave * C + lane];
    double v1 = (double)X[wave * C + 64 + lane];
    double s = v0 * v0 + v1 * v1;
    #pragma unroll
    for (int off = 32; off > 0; off >>= 1) s += __shfl_down(s, off, 64);
    if (lane == 0) sq[wave] = s;
}

// ---------------------------------------------------------------------------
// JAX threefry2x32: uniform(key(1), (1,8192))
// ---------------------------------------------------------------------------
__global__ void noise_kernel(float* __restrict__ noise) {
    int j = blockIdx.x * blockDim.x + threadIdx.x;
    if (j >= N / 2) return;
    const unsigned ks0 = 0u, ks1 = 1u;
    const unsigned ks2 = 0x1BD11BDAu ^ ks0 ^ ks1;
    unsigned x0 = (unsigned)j + ks0;
    unsigned x1 = (unsigned)(j + N / 2) + ks1;
    const unsigned rotA[4] = {13u, 15u, 26u, 6u};
    const unsigned rotB[4] = {17u, 29u, 16u, 24u};
    #pragma unroll
    for (int r = 0; r < 4; r++) { x0 += x1; x1 = rotl32(x1, rotA[r]); x1 ^= x0; }
    x0 += ks1; x1 += ks2 + 1u;
    #pragma unroll
    for (int r = 0; r < 4; r++) { x0 += x1; x1 = rotl32(x1, rotB[r]); x1 ^= x0; }
    x0 += ks2; x1 += ks0 + 2u;
    #pragma unroll
    for (int r = 0; r < 4; r++) { x0 += x1; x1 = rotl32(x1, rotA[r]); x1 ^= x0; }
    x0 += ks0; x1 += ks1 + 3u;
    #pragma unroll
    for (int r = 0; r < 4; r++) { x0 += x1; x1 = rotl32(x1, rotB[r]); x1 ^= x0; }
    x0 += ks1; x1 += ks2 + 4u;
    #pragma unroll
    for (int r = 0; r < 4; r++) { x0 += x1; x1 = rotl32(x1, rotA[r]); x1 ^= x0; }
    x0 += ks2; x1 += ks0 + 5u;
    unsigned b0 = (x0 >> 9) | 0x3f800000u;
    unsigned b1 = (x1 >> 9) | 0x3f800000u;
    noise[j]         = __uint_as_float(b0) - 1.0f;
    noise[j + N / 2] = __uint_as_float(b1) - 1.0f;
}

// p = bj*(bj+1)/2 + bi, bi <= bj
static __device__ __forceinline__ void pair_decode(int p, int& bi, int& bj) {
    int b = (int)((sqrt(8.0 * (double)p + 1.0) - 1.0) * 0.5);
    while ((b + 1) * (b + 2) / 2 <= p) b++;
    while (b * (b + 1) / 2 > p) b--;
    bj = b;
    bi = p - b * (b + 1) / 2;
}

// ---------------------------------------------------------------------------
// Shared GEMM body: 128x128 tile-pair, 8x8 per thread, row-major f64 staging.
// Rows owned by thread: 2ty+32h+rp (h<4, rp<2); cols: 2tx+32g+sp.
// ---------------------------------------------------------------------------
#define GEMM_BODY(acc, As, Bs, X4, i0, j0, t, tx, ty)                          \
    for (int ck = 0; ck < 4; ck++) {                                           \
        if (ck) __syncthreads();                                               \
        _Pragma("unroll")                                                      \
        for (int q = 0; q < 4; q++) {                                          \
            int flat = t + 256 * q;                                            \
            int row = flat >> 3, c4 = flat & 7;                                \
            float4 va = X4[(size_t)(i0 + row) * 32 + ck * 8 + c4];             \
            float4 vb = X4[(size_t)(j0 + row) * 32 + ck * 8 + c4];             \
            double* da = &As[row * CP + 4 * c4];                               \
            double* db = &Bs[row * CP + 4 * c4];                               \
            da[0] = (double)va.x; da[1] = (double)va.y;                        \
            da[2] = (double)va.z; da[3] = (double)va.w;                        \
            db[0] = (double)vb.x; db[1] = (double)vb.y;                        \
            db[2] = (double)vb.z; db[3] = (double)vb.w;                        \
        }                                                                      \
        __syncthreads();                                                       \
        _Pragma("unroll 2")                                                    \
        for (int c = 0; c < CH; c++) {                                         \
            double a[8], b[8];                                                 \
            _Pragma("unroll")                                                  \
            for (int h = 0; h < 4; h++) {                                      \
                a[2*h]   = As[(2*ty + 32*h) * CP + c];                         \
                a[2*h+1] = As[(2*ty + 32*h + 1) * CP + c];                     \
                b[2*h]   = Bs[(2*tx + 32*h) * CP + c];                         \
                b[2*h+1] = Bs[(2*tx + 32*h + 1) * CP + c];                     \
            }                                                                  \
            _Pragma("unroll")                                                  \
            for (int r = 0; r < 8; r++)                                        \
                _Pragma("unroll")                                              \
                for (int s = 0; s < 8; s++)                                    \
                    acc[r][s] += a[r] * b[s];                                  \
        }                                                                      \
    }                                                                          \
    __syncthreads();

// ---------------------------------------------------------------------------
// symA: tile-pair GEMM + per-row/per-col top-5 (register + LDS merge) + d2max.
// ---------------------------------------------------------------------------
__launch_bounds__(256, 2)
__global__ void symA_kernel(const float* __restrict__ X,
                            const double* __restrict__ sq,
                            double* __restrict__ rec_dir,
                            double* __restrict__ rec_tr,
                            unsigned long long* __restrict__ d2max_p)
{
    __shared__ __align__(16) double S[2 * TP * CP];   // 67,584 B
    __shared__ double wred[4];
    double* As = S;
    double* Bs = S + TP * CP;

    const int t  = threadIdx.x;
    const int tx = t & 15;
    const int ty = t >> 4;
    int bi, bj;
    pair_decode(blockIdx.x, bi, bj);
    const int i0 = bi * TP, j0 = bj * TP;
    const float4* X4 = (const float4*)X;

    double acc[8][8];
    #pragma unroll
    for (int r = 0; r < 8; r++)
        #pragma unroll
        for (int s = 0; s < 8; s++) acc[r][s] = 0.0;

    GEMM_BODY(acc, As, Bs, X4, i0, j0, t, tx, ty)

    // d2 in place + block max
    double sqa[8], sqj[8];
    #pragma unroll
    for (int h = 0; h < 4; h++) {
        sqa[2*h]   = sq[i0 + 2*ty + 32*h];
        sqa[2*h+1] = sq[i0 + 2*ty + 32*h + 1];
        sqj[2*h]   = sq[j0 + 2*tx + 32*h];
        sqj[2*h+1] = sq[j0 + 2*tx + 32*h + 1];
    }
    double rmax = 0.0;
    #pragma unroll
    for (int r = 0; r < 8; r++)
        #pragma unroll
        for (int s = 0; s < 8; s++) {
            double v = sqa[r] + sqj[s] - 2.0 * acc[r][s];
            acc[r][s] = v;
            rmax = fmax(rmax, v);
        }
    #pragma unroll
    for (int off = 32; off > 0; off >>= 1) rmax = fmax(rmax, __shfl_down(rmax, off, 64));
    if ((t & 63) == 0) wred[t >> 6] = rmax;

    // row top-5: two phases of 64 rows; M[64][MP] in reused S
    double* M = S;
    #pragma unroll
    for (int hp = 0; hp < 2; hp++) {
        __syncthreads();
        #pragma unroll
        for (int h2 = 0; h2 < 2; h2++) {
            #pragma unroll
            for (int rp = 0; rp < 2; rp++) {
                int r = 2 * (2 * hp + h2) + rp;
                double m5[KNN];
                #pragma unroll
                for (int k = 0; k < KNN; k++) m5[k] = 1e300;
                #pragma unroll
                for (int s = 0; s < 8; s++) ins5(m5, acc[r][s]);
                int lr = 32 * h2 + 2 * ty + rp;
                #pragma unroll
                for (int k = 0; k < KNN; k++) M[lr * MP + tx * KNN + k] = m5[k];
            }
        }
        __syncthreads();
        if (t < 64) {
            double m5[KNN];
            #pragma unroll
            for (int k = 0; k < KNN; k++) m5[k] = 1e300;
            const double* row = &M[t * MP];
            for (int q = 0; q < 80; q++) ins5(m5, row[q]);
            double* outp = &rec_dir[(size_t)blockIdx.x * (TP * KNN) + (64 * hp + t) * KNN];
            #pragma unroll
            for (int k = 0; k < KNN; k++) outp[k] = m5[k];
        }
    }

    // col top-5 (off-diagonal only)
    if (bi != bj) {
        #pragma unroll
        for (int gp = 0; gp < 2; gp++) {
            __syncthreads();
            #pragma unroll
            for (int g2 = 0; g2 < 2; g2++) {
                #pragma unroll
                for (int sp = 0; sp < 2; sp++) {
                    int s = 2 * (2 * gp + g2) + sp;
                    double m5[KNN];
                    #pragma unroll
                    for (int k = 0; k < KNN; k++) m5[k] = 1e300;
                    #pragma unroll
                    for (int r = 0; r < 8; r++) ins5(m5, acc[r][s]);
                    int lc = 32 * g2 + 2 * tx + sp;
                    #pragma unroll
                    for (int k = 0; k < KNN; k++) M[lc * MP + ty * KNN + k] = m5[k];
                }
            }
            __syncthreads();
            if (t < 64) {
                double m5[KNN];
                #pragma unroll
                for (int k = 0; k < KNN; k++) m5[k] = 1e300;
                const double* row = &M[t * MP];
                for (int q = 0; q < 80; q++) ins5(m5, row[q]);
                double* outp = &rec_tr[(size_t)blockIdx.x * (TP * KNN) + (64 * gp + t) * KNN];
                #pragma unroll
                for (int k = 0; k < KNN; k++) outp[k] = m5[k];
            }
        }
    }

    if (t == 0)
        atomicMax(d2max_p, (unsigned long long)__double_as_longlong(
            fmax(fmax(fmax(wred[0], wred[1]), fmax(wred[2], wred[3])), 0.0)));
}

// ---------------------------------------------------------------------------
// Merge symA records -> density.
// ---------------------------------------------------------------------------
__global__ void density_merge_sym_kernel(const double* __restrict__ rec_dir,
                                         const double* __restrict__ rec_tr,
                                         const float* __restrict__ noise,
                                         double* __restrict__ density)
{
    int i = blockIdx.x * blockDim.x + threadIdx.x;
    if (i >= N) return;
    int T = i >> 7, r = i & 127;
    double t5[KNN];
    #pragma unroll
    for (int k = 0; k < KNN; k++) t5[k] = 1e300;

    for (int bj = T; bj < NTILE; bj++) {
        int p = bj * (bj + 1) / 2 + T;
        const double* rp = &rec_dir[(size_t)p * (TP * KNN) + r * KNN];
        #pragma unroll
        for (int k = 0; k < KNN; k++) ins5(t5, rp[k]);
    }
    int cumT = T * (T + 1) / 2;
    for (int b2 = 0; b2 < T; b2++) {
        const double* rp = &rec_tr[(size_t)(cumT + b2) * (TP * KNN) + r * KNN];
        #pragma unroll
        for (int k = 0; k < KNN; k++) ins5(t5, rp[k]);
    }
    for (int a = 1; a < KNN; a++) {
        double key = t5[a]; int b = a - 1;
        while (b >= 0 && t5[b] > key) { t5[b + 1] = t5[b]; b--; }
        t5[b + 1] = key;
    }
    double s2 = 0.0;
    #pragma unroll
    for (int k = 0; k < KNN; k++) {
        double z = t5[k] > 0.0 ? t5[k] : 0.0;
        double d = sqrt(z) / SQRT_C;
        s2 += d * d;
    }
    density[i] = exp(-s2 / 5.0) + (double)(noise[i] * 1e-6f);
}

// ---------------------------------------------------------------------------
// symB: tile-pair GEMM + masked row/col mins in registers; LDS merge; atomicMin.
// ---------------------------------------------------------------------------
__launch_bounds__(256, 2)
__global__ void symB_kernel(const float* __restrict__ X,
                            const double* __restrict__ sq,
                            const double* __restrict__ density,
                            unsigned long long* __restrict__ gmin)
{
    __shared__ __align__(16) double S[2 * TP * CP];
    __shared__ double Drow[TP], Dcol[TP];
    double* As = S;
    double* Bs = S + TP * CP;

    const int t  = threadIdx.x;
    const int tx = t & 15;
    const int ty = t >> 4;
    int bi, bj;
    pair_decode(blockIdx.x, bi, bj);
    const int i0 = bi * TP, j0 = bj * TP;
    const float4* X4 = (const float4*)X;

    if (t < 128) Drow[t] = density[i0 + t];
    else Dcol[t - 128] = density[j0 + t - 128];

    double acc[8][8];
    #pragma unroll
    for (int r = 0; r < 8; r++)
        #pragma unroll
        for (int s = 0; s < 8; s++) acc[r][s] = 0.0;

    GEMM_BODY(acc, As, Bs, X4, i0, j0, t, tx, ty)

    double sqa[8], sqj[8], di[8], dj[8], dmr[8], dmc[8];
    #pragma unroll
    for (int h = 0; h < 4; h++) {
        sqa[2*h]   = sq[i0 + 2*ty + 32*h];
        sqa[2*h+1] = sq[i0 + 2*ty + 32*h + 1];
        sqj[2*h]   = sq[j0 + 2*tx + 32*h];
        sqj[2*h+1] = sq[j0 + 2*tx + 32*h + 1];
        di[2*h]   = Drow[2*ty + 32*h];
        di[2*h+1] = Drow[2*ty + 32*h + 1];
        dj[2*h]   = Dcol[2*tx + 32*h];
        dj[2*h+1] = Dcol[2*tx + 32*h + 1];
    }
    #pragma unroll
    for (int r = 0; r < 8; r++) { dmr[r] = 1e300; dmc[r] = 1e300; }

    #pragma unroll
    for (int r = 0; r < 8; r++)
        #pragma unroll
        for (int s = 0; s < 8; s++) {
            double v = sqa[r] + sqj[s] - 2.0 * acc[r][s];
            if (dj[s] > di[r]) dmr[r] = fmin(dmr[r], v);
            if (di[r] > dj[s]) dmc[s] = fmin(dmc[s], v);
        }

    // row merge: Mr[128][17]
    double* Mr = S;
    #pragma unroll
    for (int h = 0; h < 4; h++) {
        Mr[(2*ty + 32*h) * 17 + tx]     = dmr[2*h];
        Mr[(2*ty + 32*h + 1) * 17 + tx] = dmr[2*h + 1];
    }
    __syncthreads();
    if (t < 128) {
        double m = 1e300;
        const double* row = &Mr[t * 17];
        #pragma unroll
        for (int q = 0; q < 16; q++) m = fmin(m, row[q]);
        if (m < 9.9e299) atomicMin(&gmin[i0 + t], dmap(m));
    }
    if (bi != bj) {
        __syncthreads();
        #pragma unroll
        for (int g = 0; g < 4; g++) {
            Mr[(2*tx + 32*g) * 17 + ty]     = dmc[2*g];
            Mr[(2*tx + 32*g + 1) * 17 + ty] = dmc[2*g + 1];
        }
        __syncthreads();
        if (t < 128) {
            double m = 1e300;
            const double* row = &Mr[t * 17];
            #pragma unroll
            for (int q = 0; q < 16; q++) m = fmin(m, row[q]);
            if (m < 9.9e299) atomicMin(&gmin[j0 + t], dmap(m));
        }
    }
}

// ---------------------------------------------------------------------------
__global__ void score_sym_kernel(const unsigned long long* __restrict__ gmin,
                                 const double* __restrict__ density,
                                 const unsigned long long* __restrict__ d2max_p,
                                 double* __restrict__ score)
{
    int i = blockIdx.x * blockDim.x + threadIdx.x;
    if (i >= N) return;
    unsigned long long u = gmin[i];
    double d2m = __longlong_as_double((long long)(*d2max_p));
    double distmax = sqrt(fmax(d2m, 0.0)) / SQRT_C;
    double dp;
    if (u == 0xFFFFFFFFFFFFFFFFull) {
        dp = distmax;
    } else {
        double dmin = dunmap(u);
        dp = sqrt(fmax(dmin, 0.0)) / SQRT_C;
    }
    score[i] = dp * density[i];
}

// ---------------------------------------------------------------------------
// Stable descending rank; 256 blocks, 8-way j-split per row, shuffle reduce.
// ---------------------------------------------------------------------------
__launch_bounds__(256)
__global__ void rank_kernel(const double* __restrict__ score, int* __restrict__ out)
{
    __shared__ double Ss[N];   // 64 KB
    for (int k = 0; k < N / 256; k++) {
        int idx = threadIdx.x + 256 * k;
        Ss[idx] = score[idx];
    }
    __syncthreads();
    int il = threadIdx.x >> 3;          // 0..31
    int ch = threadIdx.x & 7;           // 0..7
    int i = blockIdx.x * 32 + il;
    double si = Ss[i];
    int cnt = 0;
    for (int q = 0; q < N / 8; q++) {
        int j = ch + (q << 3);
        double sj = Ss[j];
        cnt += (sj > si) || (sj == si && j < i);
    }
    cnt += __shfl_down(cnt, 4, 8);
    cnt += __shfl_down(cnt, 2, 8);
    cnt += __shfl_down(cnt, 1, 8);
    if (ch == 0 && cnt < NC) out[cnt] = i;
}

// ---------------------------------------------------------------------------
extern "C" void kernel_launch(void* const* d_in, const int* in_sizes, int n_in,
                              void* d_out, int out_size, void* d_ws, size_t ws_size,
                              hipStream_t stream) {
    const float* X = (const float*)d_in[0];
    int* out = (int*)d_out;

    double* ws      = (double*)d_ws;
    double* sq      = ws;                      // 8192
    double* density = ws + 8192;               // 8192
    double* score   = ws + 16384;              // 8192
    unsigned long long* d2max = (unsigned long long*)(ws + 24576);
    unsigned long long* gmin  = (unsigned long long*)(ws + 24584);  // 8192
    float*  noise   = (float*)(ws + 32776);    // 8192 floats

    const size_t rec_bytes = (size_t)NPAIR * TP * KNN * sizeof(double);  // 10.65 MB
    const size_t base_need = 4ull * 1024 * 1024;
    // R4-R7 confirmed ws_size >= 46.5 MB; new total need ~25.3 MB.
    double* rec_dir = (double*)((char*)d_ws + base_need);
    double* rec_tr  = (double*)((char*)d_ws + base_need + rec_bytes);

    init_kernel<<<N / 256, 256, 0, stream>>>(d2max, gmin);
    sq_kernel<<<N / 4, 256, 0, stream>>>(X, sq);
    noise_kernel<<<(N / 2) / 256, 256, 0, stream>>>(noise);

    symA_kernel<<<NPAIR, 256, 0, stream>>>(X, sq, rec_dir, rec_tr, d2max);
    density_merge_sym_kernel<<<N / 256, 256, 0, stream>>>(rec_dir, rec_tr, noise, density);
    symB_kernel<<<NPAIR, 256, 0, stream>>>(X, sq, density, gmin);
    score_sym_kernel<<<N / 256, 256, 0, stream>>>(gmin, density, d2max, score);
    rank_kernel<<<N / 32, 256, 0, stream>>>(score, out);
}